// Round 4
// baseline (153.807 us; speedup 1.0000x reference)
//
#include <hip/hip_runtime.h>
#include <math.h>

#define NSRC 1000
#define NTGT 100
#define NCLS 256
#define NB   32
#define NSP  1024                 // padded column count for LSA
#define PAD_IDX(j) ((j) + ((j) >> 4))
#define LDSN (NSP + (NSP >> 4))   // 1088 padded LDS entries

// ---------------- per-(b,s) logsumexp over 256 classes ----------------------
// 1000 blocks x 256 threads; each wave handles 8 consecutive rows.
__global__ __launch_bounds__(256) void lse_kernel(const float* __restrict__ logits,
                                                  float* __restrict__ lse) {
    int wid  = threadIdx.x >> 6;
    int lane = threadIdx.x & 63;
    int row0 = blockIdx.x * 32 + wid * 8;
    #pragma unroll 2
    for (int r = 0; r < 8; ++r) {
        int row = row0 + r;
        float4 v4 = reinterpret_cast<const float4*>(logits + (size_t)row * NCLS)[lane];
        float m = fmaxf(fmaxf(v4.x, v4.y), fmaxf(v4.z, v4.w));
        #pragma unroll
        for (int off = 32; off >= 1; off >>= 1) m = fmaxf(m, __shfl_xor(m, off));
        float s = expf(v4.x - m) + expf(v4.y - m) + expf(v4.z - m) + expf(v4.w - m);
        #pragma unroll
        for (int off = 32; off >= 1; off >>= 1) s += __shfl_xor(s, off);
        if (lane == 0) lse[row] = m + logf(s);
    }
}

// ---------------- transposed cost row + fused row-min reduction -------------
// One block per (b,t); b = blockIdx&31 so batch b's blocks share XCD b%8
// (logits slab cached once per XCD; cost rows written through the L2 that
// lsa block b will read). Also computes min/argmin of the row -> urow/jmin.
__global__ __launch_bounds__(256) void cost_kernel(const float* __restrict__ logits,
                                                   const int*   __restrict__ tcls,
                                                   const float* __restrict__ sbox,
                                                   const float* __restrict__ tbox,
                                                   const float* __restrict__ lse,
                                                   float*       __restrict__ cost,
                                                   float*       __restrict__ urow_g,
                                                   int*         __restrict__ jmin_g) {
    int b  = blockIdx.x & 31;
    int t  = blockIdx.x >> 5;
    int bt = b * NTGT + t;
    int cls = tcls[bt];
    float4 tb = reinterpret_cast<const float4*>(tbox)[bt];
    float area_t = (tb.z - tb.x) * (tb.w - tb.y);
    float* crow = cost + (size_t)bt * NSP;
    float m = 1e38f; int mi = 0x7fffffff;
    for (int s = threadIdx.x; s < NSP; s += 256) {
        if (s >= NSRC) { crow[s] = 1e30f; continue; }
        int gs = b * NSRC + s;
        float4 sb = reinterpret_cast<const float4*>(sbox)[gs];
        float ce = lse[gs] - logits[(size_t)gs * NCLS + cls];
        float ix1 = fmaxf(sb.x, tb.x), iy1 = fmaxf(sb.y, tb.y);
        float ix2 = fminf(sb.z, tb.z), iy2 = fminf(sb.w, tb.w);
        float inter = fmaxf(ix2 - ix1, 0.f) * fmaxf(iy2 - iy1, 0.f);
        float area_s = (sb.z - sb.x) * (sb.w - sb.y);
        float uni = area_s + area_t - inter;
        float iou = inter / uni;
        float cx1 = fminf(sb.x, tb.x), cy1 = fminf(sb.y, tb.y);
        float cx2 = fmaxf(sb.z, tb.z), cy2 = fmaxf(sb.w, tb.w);
        float carea = (cx2 - cx1) * (cy2 - cy1);
        float giou = iou - (carea - uni) / carea;
        float l1 = 0.25f * (fabsf(sb.x - tb.x) + fabsf(sb.y - tb.y) +
                            fabsf(sb.z - tb.z) + fabsf(sb.w - tb.w));
        float c = ce + 10.0f * (1.0f - giou) + l1;
        crow[s] = c;
        if (c < m) { m = c; mi = s; }
    }
    // wave reduce (min, argmin; lowest index on ties)
    #pragma unroll
    for (int off = 32; off >= 1; off >>= 1) {
        float om = __shfl_xor(m, off);
        int   oi = __shfl_xor(mi, off);
        if (om < m || (om == m && oi < mi)) { m = om; mi = oi; }
    }
    __shared__ float smin[4];
    __shared__ int   sidx[4];
    int wid = threadIdx.x >> 6, lane = threadIdx.x & 63;
    if (lane == 0) { smin[wid] = m; sidx[wid] = mi; }
    __syncthreads();
    if (threadIdx.x == 0) {
        #pragma unroll
        for (int w = 1; w < 4; ++w) {
            float om = smin[w]; int oi = sidx[w];
            if (om < m || (om == m && oi < mi)) { m = om; mi = oi; }
        }
        urow_g[bt] = m;
        jmin_g[bt] = mi;
    }
}

// ---------------- JV: greedy claim -> auction -> Dijkstra fallback ----------
// One wave per batch.
// Phase A: claim precomputed argmin columns (lowest row wins); u[i]=rowmin.
// Phase B (auction / JV augmenting row reduction): each loser row scans its
//   row with CURRENT v, finds two smallest m1@j1, m2; sets u[i]=m2, claims j1
//   (kicking occupant onto queue), v[j1] -= (m2-m1). Feasibility invariant:
//   slack >= 0 at claim time, and v only decreases afterwards (slack grows).
// Phase C: shortest augmenting path (Dijkstra) for any leftover (cap safety).
__global__ __launch_bounds__(64) void lsa_kernel(const float* __restrict__ cost,
                                                 const float* __restrict__ urow_g,
                                                 const int*   __restrict__ jmin_g,
                                                 float* __restrict__ out) {
    int b    = blockIdx.x;
    int lane = threadIdx.x;
    const float* C = cost + (size_t)b * NTGT * NSP;
    __shared__ int   way[LDSN];     // pred chain; reused as claim[] first
    __shared__ int   pcol[LDSN];    // col -> assigned row
    __shared__ float uu[LDSN];      // col -> u of its assigned row
    __shared__ float urow[NTGT];    // row dual u
    __shared__ int   jmin[NTGT];    // row argmin column (v=0)
    __shared__ int   done[NTGT];    // currently assigned?
    __shared__ int   queue[512];    // auction queue of unassigned rows
    for (int t = lane; t < LDSN; t += 64) { pcol[t] = -1; uu[t] = 0.f; way[t] = 0x7fffffff; }
    for (int t = lane; t < NTGT; t += 64) {
        urow[t] = urow_g[b * NTGT + t];
        jmin[t] = jmin_g[b * NTGT + t];
    }
    float v[16], d[16];
    #pragma unroll
    for (int k = 0; k < 16; ++k) v[k] = 0.f;
    int base = lane * 16;
    __syncthreads();

    // ---- Phase A: claim argmin columns (lowest row index wins)
    for (int r = lane; r < NTGT; r += 64) atomicMin(&way[PAD_IDX(jmin[r])], r);
    __syncthreads();
    for (int r = lane; r < NTGT; r += 64) {
        int j = jmin[r];
        int w = (way[PAD_IDX(j)] == r) ? 1 : 0;
        done[r] = w;
        if (w) { pcol[PAD_IDX(j)] = r; uu[PAD_IDX(j)] = urow[r]; }
    }
    __syncthreads();

    // ---- Phase B: auction. Queue starts with phase-A losers.
    int qh = 0, qt = 0;
    for (int r = 0; r < NTGT; ++r) {      // uniform loop, LDS broadcast reads
        if (!done[r]) { if (lane == 0) queue[qt] = r; qt++; }
    }
    __syncthreads();
    int steps = 0;
    while (qh < qt && steps < 400) {
        ++steps;
        int i = queue[qh++];              // uniform broadcast read
        // two smallest of c[i][j] - v[j]
        const float4* row4 = reinterpret_cast<const float4*>(C + (size_t)i * NSP + base);
        float m1 = 1e38f, m2 = 1e38f; int j1 = 0x7fffffff;
        #pragma unroll
        for (int q = 0; q < 4; ++q) {
            float4 c4 = row4[q];
            float vals[4] = {c4.x - v[4*q+0], c4.y - v[4*q+1],
                             c4.z - v[4*q+2], c4.w - v[4*q+3]};
            #pragma unroll
            for (int e = 0; e < 4; ++e) {
                float val = vals[e];
                if (val < m1) { m2 = m1; m1 = val; j1 = base + 4*q + e; }
                else m2 = fminf(m2, val);
            }
        }
        #pragma unroll
        for (int off = 32; off >= 1; off >>= 1) {
            float om1 = __shfl_xor(m1, off);
            float om2 = __shfl_xor(m2, off);
            int   oj1 = __shfl_xor(j1, off);
            bool take = (om1 < m1) || (om1 == m1 && oj1 < j1);
            float lose = take ? m1 : om1;
            m1 = take ? om1 : m1;
            j1 = take ? oj1 : j1;
            m2 = fminf(fminf(m2, om2), lose);
        }
        // claim j1 for row i with u[i]=m2; kick occupant; v[j1] -= m2-m1
        int old = pcol[PAD_IDX(j1)];      // uniform broadcast read
        if ((j1 >> 4) == lane) v[j1 & 15] -= (m2 - m1);
        if (lane == 0) {
            pcol[PAD_IDX(j1)] = i;
            uu[PAD_IDX(j1)]   = m2;
            urow[i] = m2;
            done[i] = 1;
            if (old >= 0) { queue[qt] = old; done[old] = 0; }
        }
        if (old >= 0) qt++;
        __syncthreads();                  // single wave: cheap; orders LDS for all lanes
    }
    __syncthreads();

    // ---- Phase C: shortest augmenting path for any leftover rows
    for (int i = 0; i < NTGT; ++i) {
        if (done[i]) continue;                 // uniform across wave (LDS broadcast)
        float ui = urow[i];
        {
            const float4* row4 = reinterpret_cast<const float4*>(C + (size_t)i * NSP + base);
            #pragma unroll
            for (int q = 0; q < 4; ++q) {
                float4 c4 = row4[q];
                d[4*q+0] = c4.x - ui - v[4*q+0];
                d[4*q+1] = c4.y - ui - v[4*q+1];
                d[4*q+2] = c4.z - ui - v[4*q+2];
                d[4*q+3] = c4.w - ui - v[4*q+3];
            }
        }
        #pragma unroll
        for (int k = 0; k < 16; ++k) way[PAD_IDX(base + k)] = -1;
        unsigned int used = 0;
        float Df = 0.f;
        int jf = -1;

        for (int it = 0; it < NTGT + 3; ++it) {
            float lmin = 1e38f;
            #pragma unroll
            for (int k = 0; k < 16; ++k) {
                float val = ((used >> k) & 1u) ? 1e38f : d[k];
                lmin = fminf(lmin, val);
            }
            float wmin = lmin;
            #pragma unroll
            for (int off = 32; off >= 1; off >>= 1) wmin = fminf(wmin, __shfl_xor(wmin, off));
            unsigned long long msk = __ballot(lmin == wmin);
            int src = __ffsll(msk) - 1;
            int myk = -1;
            #pragma unroll
            for (int k = 15; k >= 0; --k)
                if (!((used >> k) & 1u) && d[k] == wmin) myk = k;
            int j0 = __shfl(base + myk, src);
            if (j0 < 0) break;                    // NaN safety net
            int pj0 = pcol[PAD_IDX(j0)];
            if (pj0 < 0) { Df = wmin; jf = j0; break; }   // reached a free column
            if ((j0 >> 4) == lane) used |= 1u << (j0 & 15);
            float uref = uu[PAD_IDX(j0)];
            float sft  = wmin - uref;             // dist(j0) - u[row(j0)]
            const float4* rr = reinterpret_cast<const float4*>(C + (size_t)pj0 * NSP + base);
            float cr[16];
            #pragma unroll
            for (int q = 0; q < 4; ++q) {
                float4 c4 = rr[q];
                cr[4*q+0] = c4.x; cr[4*q+1] = c4.y; cr[4*q+2] = c4.z; cr[4*q+3] = c4.w;
            }
            #pragma unroll
            for (int k = 0; k < 16; ++k) {
                float cand = sft + cr[k] - v[k];
                bool upd = (cand < d[k]) && !((used >> k) & 1u);
                if (upd) { d[k] = cand; way[PAD_IDX(base + k)] = j0; }
            }
        }

        // dual updates for scanned columns: v -= (Df - d), u[row] += (Df - d)
        if (jf >= 0) {
            #pragma unroll
            for (int k = 0; k < 16; ++k) {
                if ((used >> k) & 1u) {
                    float diff = Df - d[k];
                    v[k] -= diff;
                    uu[PAD_IDX(base + k)] += diff;
                }
            }
        }
        __syncthreads();
        // augment: walk predecessor chain, shifting rows (and their u) forward
        if (lane == 0 && jf >= 0) {
            int j = jf;
            for (int g = 0; g < NSP; ++g) {
                int jp = way[PAD_IDX(j)];
                if (jp < 0) { pcol[PAD_IDX(j)] = i; uu[PAD_IDX(j)] = ui + Df; break; }
                pcol[PAD_IDX(j)] = pcol[PAD_IDX(jp)];
                uu[PAD_IDX(j)]   = uu[PAD_IDX(jp)];
                j = jp;
            }
            done[i] = 1;
        }
        __syncthreads();
    }

    // mean of matched costs
    float acc = 0.f;
    #pragma unroll
    for (int k = 0; k < 16; ++k) {
        int j = base + k;
        if (j < NSRC) {
            int r = pcol[PAD_IDX(j)];
            if (r >= 0) acc += C[(size_t)r * NSP + j];
        }
    }
    #pragma unroll
    for (int off = 32; off >= 1; off >>= 1) acc += __shfl_xor(acc, off);
    if (lane == 0) out[b] = acc * (1.0f / NTGT);
}

extern "C" void kernel_launch(void* const* d_in, const int* in_sizes, int n_in,
                              void* d_out, int out_size, void* d_ws, size_t ws_size,
                              hipStream_t stream) {
    const float* logits = (const float*)d_in[0];   // (32,1000,256) f32
    const int*   tcls   = (const int*)  d_in[1];   // (32,100) i32
    const float* sbox   = (const float*)d_in[2];   // (32,1000,4) f32
    const float* tbox   = (const float*)d_in[3];   // (32,100,4) f32
    float* out = (float*)d_out;                    // (32,) f32

    float* lse    = (float*)d_ws;                  // 32768 floats (32000 used)
    float* cost   = lse + 32768;                   // 32*100*1024 floats (~13.1 MB)
    float* urow_g = cost + (size_t)NB * NTGT * NSP; // 3200 floats
    int*   jmin_g = (int*)(urow_g + NB * NTGT);     // 3200 ints

    lse_kernel <<<1000,      256, 0, stream>>>(logits, lse);
    cost_kernel<<<NB * NTGT, 256, 0, stream>>>(logits, tcls, sbox, tbox, lse, cost,
                                               urow_g, jmin_g);
    lsa_kernel <<<NB,        64,  0, stream>>>(cost, urow_g, jmin_g, out);
}

// Round 5
// 150.689 us; speedup vs baseline: 1.0207x; 1.0207x over previous
//
#include <hip/hip_runtime.h>
#include <math.h>

#define NSRC 1000
#define NTGT 100
#define NCLS 256
#define NB   32
#define NSP  1024                 // padded column count for LSA
#define PAD_IDX(j) ((j) + ((j) >> 4))
#define LDSN (NSP + (NSP >> 4))   // 1088 padded LDS entries
#define AUCTION_EPS 0.01f

// ---------------- per-(b,s) logsumexp over 256 classes ----------------------
__global__ __launch_bounds__(256) void lse_kernel(const float* __restrict__ logits,
                                                  float* __restrict__ lse) {
    int wid  = threadIdx.x >> 6;
    int lane = threadIdx.x & 63;
    int row0 = blockIdx.x * 32 + wid * 8;
    #pragma unroll 2
    for (int r = 0; r < 8; ++r) {
        int row = row0 + r;
        float4 v4 = reinterpret_cast<const float4*>(logits + (size_t)row * NCLS)[lane];
        float m = fmaxf(fmaxf(v4.x, v4.y), fmaxf(v4.z, v4.w));
        #pragma unroll
        for (int off = 32; off >= 1; off >>= 1) m = fmaxf(m, __shfl_xor(m, off));
        float s = expf(v4.x - m) + expf(v4.y - m) + expf(v4.z - m) + expf(v4.w - m);
        #pragma unroll
        for (int off = 32; off >= 1; off >>= 1) s += __shfl_xor(s, off);
        if (lane == 0) lse[row] = m + logf(s);
    }
}

// ---------------- transposed cost row + fused top-2 row reduction -----------
// One block per (b,t); b = blockIdx&31 (XCD locality). Produces the row's
// two smallest values m1@j1, m2 for the auction's precomputed first bids.
__global__ __launch_bounds__(256) void cost_kernel(const float* __restrict__ logits,
                                                   const int*   __restrict__ tcls,
                                                   const float* __restrict__ sbox,
                                                   const float* __restrict__ tbox,
                                                   const float* __restrict__ lse,
                                                   float*       __restrict__ cost,
                                                   float*       __restrict__ urow_g,
                                                   int*         __restrict__ jmin_g,
                                                   float*       __restrict__ m2_g) {
    int b  = blockIdx.x & 31;
    int t  = blockIdx.x >> 5;
    int bt = b * NTGT + t;
    int cls = tcls[bt];
    float4 tb = reinterpret_cast<const float4*>(tbox)[bt];
    float area_t = (tb.z - tb.x) * (tb.w - tb.y);
    float* crow = cost + (size_t)bt * NSP;
    float m1 = 1e38f, m2 = 1e38f; int mi = 0x7fffffff;
    for (int s = threadIdx.x; s < NSP; s += 256) {
        if (s >= NSRC) { crow[s] = 1e30f; continue; }
        int gs = b * NSRC + s;
        float4 sb = reinterpret_cast<const float4*>(sbox)[gs];
        float ce = lse[gs] - logits[(size_t)gs * NCLS + cls];
        float ix1 = fmaxf(sb.x, tb.x), iy1 = fmaxf(sb.y, tb.y);
        float ix2 = fminf(sb.z, tb.z), iy2 = fminf(sb.w, tb.w);
        float inter = fmaxf(ix2 - ix1, 0.f) * fmaxf(iy2 - iy1, 0.f);
        float area_s = (sb.z - sb.x) * (sb.w - sb.y);
        float uni = area_s + area_t - inter;
        float iou = inter / uni;
        float cx1 = fminf(sb.x, tb.x), cy1 = fminf(sb.y, tb.y);
        float cx2 = fmaxf(sb.z, tb.z), cy2 = fmaxf(sb.w, tb.w);
        float carea = (cx2 - cx1) * (cy2 - cy1);
        float giou = iou - (carea - uni) / carea;
        float l1 = 0.25f * (fabsf(sb.x - tb.x) + fabsf(sb.y - tb.y) +
                            fabsf(sb.z - tb.z) + fabsf(sb.w - tb.w));
        float c = ce + 10.0f * (1.0f - giou) + l1;
        crow[s] = c;
        if (c < m1) { m2 = m1; m1 = c; mi = s; }
        else if (c < m2) m2 = c;
    }
    // wave-level top-2 merge (lowest index on m1 ties)
    #pragma unroll
    for (int off = 32; off >= 1; off >>= 1) {
        float om1 = __shfl_xor(m1, off);
        float om2 = __shfl_xor(m2, off);
        int   oi  = __shfl_xor(mi, off);
        bool take = (om1 < m1) || (om1 == m1 && oi < mi);
        float lose = take ? m1 : om1;
        m1 = take ? om1 : m1;
        mi = take ? oi  : mi;
        m2 = fminf(fminf(m2, om2), lose);
    }
    __shared__ float smin[4], smin2[4];
    __shared__ int   sidx[4];
    int wid = threadIdx.x >> 6, lane = threadIdx.x & 63;
    if (lane == 0) { smin[wid] = m1; smin2[wid] = m2; sidx[wid] = mi; }
    __syncthreads();
    if (threadIdx.x == 0) {
        #pragma unroll
        for (int w = 1; w < 4; ++w) {
            float om1 = smin[w], om2 = smin2[w]; int oi = sidx[w];
            bool take = (om1 < m1) || (om1 == m1 && oi < mi);
            float lose = take ? m1 : om1;
            m1 = take ? om1 : m1;
            mi = take ? oi  : mi;
            m2 = fminf(fminf(m2, om2), lose);
        }
        urow_g[bt] = m1;
        jmin_g[bt] = mi;
        m2_g[bt]   = m2;
    }
}

// ---------------- JV: greedy claim -> eps-auction -> Dijkstra fallback ------
// One wave per batch.
// Phase A: claim precomputed argmin columns (lowest row wins); u[i]=rowmin.
// Phase B (eps-auction): bid delta = max(m2-m1, EPS); u[i]=m1+delta (matched
//   slack exactly 0; other slacks >= -EPS). Initial losers use precomputed
//   (m1,j1,m2) without a row scan while v[j1] is still 0 (LDS shadow check).
//   EPS floor guarantees strict v progress -> no tie ping-pong.
// Phase C: shortest augmenting path for leftovers (safety; tolerates -EPS).
__global__ __launch_bounds__(64) void lsa_kernel(const float* __restrict__ cost,
                                                 const float* __restrict__ urow_g,
                                                 const int*   __restrict__ jmin_g,
                                                 const float* __restrict__ m2_g,
                                                 float* __restrict__ out) {
    int b    = blockIdx.x;
    int lane = threadIdx.x;
    const float* C = cost + (size_t)b * NTGT * NSP;
    __shared__ int   way[LDSN];     // pred chain; reused as claim[] first
    __shared__ int   pcol[LDSN];    // col -> assigned row
    __shared__ float uu[LDSN];      // col -> u of its assigned row
    __shared__ float vsh[LDSN];     // shadow of column duals v (Phase B only)
    __shared__ float urow[NTGT];    // row dual u (init: row min m1)
    __shared__ float m2s[NTGT];     // row second-min (at v=0)
    __shared__ int   jmin[NTGT];    // row argmin column (at v=0)
    __shared__ int   done[NTGT];    // currently assigned?
    __shared__ int   queue[768];    // auction queue of unassigned rows
    for (int t = lane; t < LDSN; t += 64) {
        pcol[t] = -1; uu[t] = 0.f; vsh[t] = 0.f; way[t] = 0x7fffffff;
    }
    for (int t = lane; t < NTGT; t += 64) {
        urow[t] = urow_g[b * NTGT + t];
        jmin[t] = jmin_g[b * NTGT + t];
        m2s[t]  = m2_g[b * NTGT + t];
    }
    float v[16], d[16];
    #pragma unroll
    for (int k = 0; k < 16; ++k) v[k] = 0.f;
    int base = lane * 16;
    __syncthreads();

    // ---- Phase A: claim argmin columns (lowest row index wins)
    for (int r = lane; r < NTGT; r += 64) atomicMin(&way[PAD_IDX(jmin[r])], r);
    __syncthreads();
    for (int r = lane; r < NTGT; r += 64) {
        int j = jmin[r];
        int w = (way[PAD_IDX(j)] == r) ? 1 : 0;
        done[r] = w;
        if (w) { pcol[PAD_IDX(j)] = r; uu[PAD_IDX(j)] = urow[r]; }
    }
    __syncthreads();

    // ---- Phase B: eps-auction. Queue = Phase-A losers (ballot compaction).
    int qt = 0;
    #pragma unroll
    for (int r0 = 0; r0 < 128; r0 += 64) {
        int r = r0 + lane;
        bool act = (r < NTGT) && !done[r];
        unsigned long long mask = __ballot(act);
        if (act) queue[qt + __popcll(mask & ((1ull << lane) - 1ull))] = r;
        qt += __popcll(mask);
    }
    int qinit = qt;
    __syncthreads();

    int qh = 0, steps = 0;
    while (qh < qt && steps < 600) {
        ++steps;
        int  i      = queue[qh];           // uniform broadcast read
        bool isInit = (qh < qinit);
        ++qh;
        int j1; float m1, m2;
        int   pj  = jmin[i];
        float vpj = vsh[PAD_IDX(pj)];      // uniform
        if (isInit && vpj == 0.0f) {
            // precomputed first bid still valid (v[jmin] untouched, row never claimed)
            j1 = pj; m1 = urow[i]; m2 = m2s[i];
        } else {
            // full re-scan: two smallest of c[i][j] - v[j]
            const float4* row4 = reinterpret_cast<const float4*>(C + (size_t)i * NSP + base);
            m1 = 1e38f; m2 = 1e38f; j1 = 0x7fffffff;
            #pragma unroll
            for (int q = 0; q < 4; ++q) {
                float4 c4 = row4[q];
                float vals[4] = {c4.x - v[4*q+0], c4.y - v[4*q+1],
                                 c4.z - v[4*q+2], c4.w - v[4*q+3]};
                #pragma unroll
                for (int e = 0; e < 4; ++e) {
                    float val = vals[e];
                    if (val < m1) { m2 = m1; m1 = val; j1 = base + 4*q + e; }
                    else m2 = fminf(m2, val);
                }
            }
            #pragma unroll
            for (int off = 32; off >= 1; off >>= 1) {
                float om1 = __shfl_xor(m1, off);
                float om2 = __shfl_xor(m2, off);
                int   oj1 = __shfl_xor(j1, off);
                bool take = (om1 < m1) || (om1 == m1 && oj1 < j1);
                float lose = take ? m1 : om1;
                m1 = take ? om1 : m1;
                j1 = take ? oj1 : j1;
                m2 = fminf(fminf(m2, om2), lose);
            }
        }
        float delta = fmaxf(m2 - m1, AUCTION_EPS);
        int old = pcol[PAD_IDX(j1)];       // uniform broadcast read
        if ((j1 >> 4) == lane) {
            #pragma unroll
            for (int k = 0; k < 16; ++k)
                if ((j1 & 15) == k) { v[k] -= delta; vsh[PAD_IDX(j1)] = v[k]; }
        }
        if (lane == 0) {
            pcol[PAD_IDX(j1)] = i;
            uu[PAD_IDX(j1)]   = m1 + delta;   // matched slack exactly 0
            urow[i] = m1 + delta;
            done[i] = 1;
            if (old >= 0) { queue[qt] = old; done[old] = 0; }
        }
        if (old >= 0) qt++;
        __syncthreads();
    }
    __syncthreads();

    // ---- Phase C: shortest augmenting path for any leftover rows
    for (int i = 0; i < NTGT; ++i) {
        if (done[i]) continue;                 // uniform across wave
        float ui = urow[i];
        {
            const float4* row4 = reinterpret_cast<const float4*>(C + (size_t)i * NSP + base);
            #pragma unroll
            for (int q = 0; q < 4; ++q) {
                float4 c4 = row4[q];
                d[4*q+0] = c4.x - ui - v[4*q+0];
                d[4*q+1] = c4.y - ui - v[4*q+1];
                d[4*q+2] = c4.z - ui - v[4*q+2];
                d[4*q+3] = c4.w - ui - v[4*q+3];
            }
        }
        #pragma unroll
        for (int k = 0; k < 16; ++k) way[PAD_IDX(base + k)] = -1;
        unsigned int used = 0;
        float Df = 0.f;
        int jf = -1;

        for (int it = 0; it < NTGT + 3; ++it) {
            float lmin = 1e38f;
            #pragma unroll
            for (int k = 0; k < 16; ++k) {
                float val = ((used >> k) & 1u) ? 1e38f : d[k];
                lmin = fminf(lmin, val);
            }
            float wmin = lmin;
            #pragma unroll
            for (int off = 32; off >= 1; off >>= 1) wmin = fminf(wmin, __shfl_xor(wmin, off));
            unsigned long long msk = __ballot(lmin == wmin);
            int src = __ffsll(msk) - 1;
            int myk = -1;
            #pragma unroll
            for (int k = 15; k >= 0; --k)
                if (!((used >> k) & 1u) && d[k] == wmin) myk = k;
            int j0 = __shfl(base + myk, src);
            if (j0 < 0) break;                    // NaN safety net
            int pj0 = pcol[PAD_IDX(j0)];
            if (pj0 < 0) { Df = wmin; jf = j0; break; }   // reached a free column
            if ((j0 >> 4) == lane) used |= 1u << (j0 & 15);
            float uref = uu[PAD_IDX(j0)];
            float sft  = wmin - uref;             // dist(j0) - u[row(j0)]
            const float4* rr = reinterpret_cast<const float4*>(C + (size_t)pj0 * NSP + base);
            float cr[16];
            #pragma unroll
            for (int q = 0; q < 4; ++q) {
                float4 c4 = rr[q];
                cr[4*q+0] = c4.x; cr[4*q+1] = c4.y; cr[4*q+2] = c4.z; cr[4*q+3] = c4.w;
            }
            #pragma unroll
            for (int k = 0; k < 16; ++k) {
                float cand = sft + cr[k] - v[k];
                bool upd = (cand < d[k]) && !((used >> k) & 1u);
                if (upd) { d[k] = cand; way[PAD_IDX(base + k)] = j0; }
            }
        }

        // dual updates for scanned columns: v -= (Df - d), u[row] += (Df - d)
        if (jf >= 0) {
            #pragma unroll
            for (int k = 0; k < 16; ++k) {
                if ((used >> k) & 1u) {
                    float diff = Df - d[k];
                    v[k] -= diff;
                    uu[PAD_IDX(base + k)] += diff;
                }
            }
        }
        __syncthreads();
        // augment: walk predecessor chain, shifting rows (and their u) forward
        if (lane == 0 && jf >= 0) {
            int j = jf;
            for (int g = 0; g < NSP; ++g) {
                int jp = way[PAD_IDX(j)];
                if (jp < 0) { pcol[PAD_IDX(j)] = i; uu[PAD_IDX(j)] = ui + Df; break; }
                pcol[PAD_IDX(j)] = pcol[PAD_IDX(jp)];
                uu[PAD_IDX(j)]   = uu[PAD_IDX(jp)];
                j = jp;
            }
            done[i] = 1;
        }
        __syncthreads();
    }

    // mean of matched costs
    float acc = 0.f;
    #pragma unroll
    for (int k = 0; k < 16; ++k) {
        int j = base + k;
        if (j < NSRC) {
            int r = pcol[PAD_IDX(j)];
            if (r >= 0) acc += C[(size_t)r * NSP + j];
        }
    }
    #pragma unroll
    for (int off = 32; off >= 1; off >>= 1) acc += __shfl_xor(acc, off);
    if (lane == 0) out[b] = acc * (1.0f / NTGT);
}

extern "C" void kernel_launch(void* const* d_in, const int* in_sizes, int n_in,
                              void* d_out, int out_size, void* d_ws, size_t ws_size,
                              hipStream_t stream) {
    const float* logits = (const float*)d_in[0];   // (32,1000,256) f32
    const int*   tcls   = (const int*)  d_in[1];   // (32,100) i32
    const float* sbox   = (const float*)d_in[2];   // (32,1000,4) f32
    const float* tbox   = (const float*)d_in[3];   // (32,100,4) f32
    float* out = (float*)d_out;                    // (32,) f32

    float* lse    = (float*)d_ws;                  // 32768 floats (32000 used)
    float* cost   = lse + 32768;                   // 32*100*1024 floats (~13.1 MB)
    float* urow_g = cost + (size_t)NB * NTGT * NSP; // 3200 floats
    int*   jmin_g = (int*)(urow_g + NB * NTGT);     // 3200 ints
    float* m2_g   = (float*)(jmin_g + NB * NTGT);   // 3200 floats

    lse_kernel <<<1000,      256, 0, stream>>>(logits, lse);
    cost_kernel<<<NB * NTGT, 256, 0, stream>>>(logits, tcls, sbox, tbox, lse, cost,
                                               urow_g, jmin_g, m2_g);
    lsa_kernel <<<NB,        64,  0, stream>>>(cost, urow_g, jmin_g, m2_g, out);
}

// Round 7
// 128.611 us; speedup vs baseline: 1.1959x; 1.1717x over previous
//
#include <hip/hip_runtime.h>
#include <math.h>

#define NSRC 1000
#define NTGT 100
#define NCLS 256
#define NB   32
#define NSP  1024                 // padded column count for LSA
#define PAD_IDX(j) ((j) + ((j) >> 4))
#define LDSN (NSP + (NSP >> 4))   // 1088 padded LDS entries
#define AUCTION_EPS 0.01f
#define NWAVES 4
#define ROUND_CAP 128

// NOTE (R6 post-mortem): column reduction (v[j] = colmin > 0) is INVALID for
// rectangular LAP — the LP dual requires v[j] <= 0 with v[j] < 0 only on
// matched columns. All phases below keep v <= 0 (start at 0, only decrease).

// ---------------- per-(b,s) logsumexp over 256 classes ----------------------
__global__ __launch_bounds__(256) void lse_kernel(const float* __restrict__ logits,
                                                  float* __restrict__ lse) {
    int wid  = threadIdx.x >> 6;
    int lane = threadIdx.x & 63;
    int row0 = blockIdx.x * 32 + wid * 8;
    #pragma unroll 2
    for (int r = 0; r < 8; ++r) {
        int row = row0 + r;
        float4 v4 = reinterpret_cast<const float4*>(logits + (size_t)row * NCLS)[lane];
        float m = fmaxf(fmaxf(v4.x, v4.y), fmaxf(v4.z, v4.w));
        #pragma unroll
        for (int off = 32; off >= 1; off >>= 1) m = fmaxf(m, __shfl_xor(m, off));
        float s = expf(v4.x - m) + expf(v4.y - m) + expf(v4.z - m) + expf(v4.w - m);
        #pragma unroll
        for (int off = 32; off >= 1; off >>= 1) s += __shfl_xor(s, off);
        if (lane == 0) lse[row] = m + logf(s);
    }
}

// ---------------- transposed cost row + fused top-2 row reduction -----------
// (verbatim R5 — proven) One block per (b,t); b = blockIdx&31 (XCD locality).
__global__ __launch_bounds__(256) void cost_kernel(const float* __restrict__ logits,
                                                   const int*   __restrict__ tcls,
                                                   const float* __restrict__ sbox,
                                                   const float* __restrict__ tbox,
                                                   const float* __restrict__ lse,
                                                   float*       __restrict__ cost,
                                                   float*       __restrict__ urow_g,
                                                   int*         __restrict__ jmin_g,
                                                   float*       __restrict__ m2_g) {
    int b  = blockIdx.x & 31;
    int t  = blockIdx.x >> 5;
    int bt = b * NTGT + t;
    int cls = tcls[bt];
    float4 tb = reinterpret_cast<const float4*>(tbox)[bt];
    float area_t = (tb.z - tb.x) * (tb.w - tb.y);
    float* crow = cost + (size_t)bt * NSP;
    float m1 = 1e38f, m2 = 1e38f; int mi = 0x7fffffff;
    for (int s = threadIdx.x; s < NSP; s += 256) {
        if (s >= NSRC) { crow[s] = 1e30f; continue; }
        int gs = b * NSRC + s;
        float4 sb = reinterpret_cast<const float4*>(sbox)[gs];
        float ce = lse[gs] - logits[(size_t)gs * NCLS + cls];
        float ix1 = fmaxf(sb.x, tb.x), iy1 = fmaxf(sb.y, tb.y);
        float ix2 = fminf(sb.z, tb.z), iy2 = fminf(sb.w, tb.w);
        float inter = fmaxf(ix2 - ix1, 0.f) * fmaxf(iy2 - iy1, 0.f);
        float area_s = (sb.z - sb.x) * (sb.w - sb.y);
        float uni = area_s + area_t - inter;
        float iou = inter / uni;
        float cx1 = fminf(sb.x, tb.x), cy1 = fminf(sb.y, tb.y);
        float cx2 = fmaxf(sb.z, tb.z), cy2 = fmaxf(sb.w, tb.w);
        float carea = (cx2 - cx1) * (cy2 - cy1);
        float giou = iou - (carea - uni) / carea;
        float l1 = 0.25f * (fabsf(sb.x - tb.x) + fabsf(sb.y - tb.y) +
                            fabsf(sb.z - tb.z) + fabsf(sb.w - tb.w));
        float c = ce + 10.0f * (1.0f - giou) + l1;
        crow[s] = c;
        if (c < m1) { m2 = m1; m1 = c; mi = s; }
        else if (c < m2) m2 = c;
    }
    #pragma unroll
    for (int off = 32; off >= 1; off >>= 1) {
        float om1 = __shfl_xor(m1, off);
        float om2 = __shfl_xor(m2, off);
        int   oi  = __shfl_xor(mi, off);
        bool take = (om1 < m1) || (om1 == m1 && oi < mi);
        float lose = take ? m1 : om1;
        m1 = take ? om1 : m1;
        mi = take ? oi  : mi;
        m2 = fminf(fminf(m2, om2), lose);
    }
    __shared__ float smin[4], smin2[4];
    __shared__ int   sidx[4];
    int wid = threadIdx.x >> 6, lane = threadIdx.x & 63;
    if (lane == 0) { smin[wid] = m1; smin2[wid] = m2; sidx[wid] = mi; }
    __syncthreads();
    if (threadIdx.x == 0) {
        #pragma unroll
        for (int w = 1; w < 4; ++w) {
            float om1 = smin[w], om2 = smin2[w]; int oi = sidx[w];
            bool take = (om1 < m1) || (om1 == m1 && oi < mi);
            float lose = take ? m1 : om1;
            m1 = take ? om1 : m1;
            mi = take ? oi  : mi;
            m2 = fminf(fminf(m2, om2), lose);
        }
        urow_g[bt] = m1;
        jmin_g[bt] = mi;
        m2_g[bt]   = m2;
    }
}

// ---------------- JV: claim -> parallel eps-auction -> exact Dijkstra -------
// One block (256 threads = 4 waves) per batch.
// Phase A: claim precomputed argmin columns (lowest row wins); u[i]=rowmin.
// Phase B: Jacobi-scan / Gauss-Seidel-commit eps-auction. Up to 4 free rows
//   scan concurrently (one per wave: top-2 of c[i][j]-v[j]); thread 0 commits
//   bids serially with a price-staleness check (stale -> requeue). Bids
//   computed against prices that can only have dropped keep slack >= -EPS;
//   committed matched edges are exactly tight. v only decreases from 0.
// Phase C: exact shortest augmenting path (wave 0) for leftovers.
__global__ __launch_bounds__(256) void lsa_kernel(const float* __restrict__ cost,
                                                  const float* __restrict__ urow_g,
                                                  const int*   __restrict__ jmin_g,
                                                  const float* __restrict__ m2_g,
                                                  float* __restrict__ out) {
    int b    = blockIdx.x;
    int tid  = threadIdx.x;
    int wv   = tid >> 6;
    int lane = tid & 63;
    const float* C = cost + (size_t)b * NTGT * NSP;
    __shared__ int   way[LDSN];     // pred chain; reused as claim[] first
    __shared__ int   pcol[LDSN];    // col -> assigned row
    __shared__ float uu[LDSN];      // col -> u of its assigned row
    __shared__ float vsh[LDSN];     // column duals v (<= 0)
    __shared__ float urow[NTGT];    // row dual u
    __shared__ float m2s[NTGT];     // row second-min (at v=0)
    __shared__ int   jmin[NTGT];    // row argmin column (at v=0)
    __shared__ int   done[NTGT];    // currently assigned?
    __shared__ int   qbuf[1024];    // ring buffer of free rows
    __shared__ int   qstate[2];     // monotone counters: qh, qt
    __shared__ int   srow[NWAVES], scol[NWAVES];
    __shared__ float sm1[NWAVES], sm2[NWAVES], svscan[NWAVES];

    for (int t = tid; t < LDSN; t += 256) {
        pcol[t] = -1; uu[t] = 0.f; vsh[t] = 0.f; way[t] = 0x7fffffff;
    }
    for (int t = tid; t < NTGT; t += 256) {
        urow[t] = urow_g[b * NTGT + t];
        jmin[t] = jmin_g[b * NTGT + t];
        m2s[t]  = m2_g[b * NTGT + t];
    }
    if (tid == 0) { qstate[0] = 0; qstate[1] = 0; }
    __syncthreads();

    // ---- Phase A: claim argmin columns (lowest row index wins)
    for (int r = tid; r < NTGT; r += 256) atomicMin(&way[PAD_IDX(jmin[r])], r);
    __syncthreads();
    for (int r = tid; r < NTGT; r += 256) {
        int j = jmin[r];
        int w = (way[PAD_IDX(j)] == r) ? 1 : 0;
        done[r] = w;
        if (w) { pcol[PAD_IDX(j)] = r; uu[PAD_IDX(j)] = urow[r]; }
    }
    __syncthreads();

    // ---- queue build: wave 0 ballot compaction of Phase-A losers
    if (tid < 64) {
        int qt = 0;
        #pragma unroll
        for (int r0 = 0; r0 < 128; r0 += 64) {
            int r = r0 + lane;
            bool act = (r < NTGT) && !done[r];
            unsigned long long mask = __ballot(act);
            if (act) qbuf[qt + __popcll(mask & ((1ull << lane) - 1ull))] = r;
            qt += __popcll(mask);
        }
        if (lane == 0) qstate[1] = qt;
    }
    __syncthreads();

    int base = lane * 16;

    // ---- Phase B: rounds of parallel scans + serial commit
    for (int round = 0; round < ROUND_CAP; ++round) {
        int qh = qstate[0], qt = qstate[1];   // uniform after barrier
        int navail = qt - qh;
        if (navail <= 0) break;
        int take = navail < NWAVES ? navail : NWAVES;
        if (wv < take) {
            int i = qbuf[(qh + wv) & 1023];   // wave-uniform
            int j1; float m1, m2;
            int pj = jmin[i];
            if (vsh[PAD_IDX(pj)] == 0.0f) {
                // precomputed (v=0) top-2 still eps-valid: prices only drop
                j1 = pj; m1 = urow[i]; m2 = m2s[i];
            } else {
                const float4* row4 = reinterpret_cast<const float4*>(C + (size_t)i * NSP + base);
                m1 = 1e38f; m2 = 1e38f; j1 = 0x7fffffff;
                #pragma unroll
                for (int q = 0; q < 4; ++q) {
                    float4 c4 = row4[q];
                    float vals[4];
                    vals[0] = c4.x - vsh[PAD_IDX(base + 4*q + 0)];
                    vals[1] = c4.y - vsh[PAD_IDX(base + 4*q + 1)];
                    vals[2] = c4.z - vsh[PAD_IDX(base + 4*q + 2)];
                    vals[3] = c4.w - vsh[PAD_IDX(base + 4*q + 3)];
                    #pragma unroll
                    for (int e = 0; e < 4; ++e) {
                        float val = vals[e];
                        if (val < m1) { m2 = m1; m1 = val; j1 = base + 4*q + e; }
                        else m2 = fminf(m2, val);
                    }
                }
                #pragma unroll
                for (int off = 32; off >= 1; off >>= 1) {
                    float om1 = __shfl_xor(m1, off);
                    float om2 = __shfl_xor(m2, off);
                    int   oj1 = __shfl_xor(j1, off);
                    bool take2 = (om1 < m1) || (om1 == m1 && oj1 < j1);
                    float lose = take2 ? m1 : om1;
                    m1 = take2 ? om1 : m1;
                    j1 = take2 ? oj1 : j1;
                    m2 = fminf(fminf(m2, om2), lose);
                }
            }
            if (lane == 0) {
                srow[wv] = i; scol[wv] = j1; sm1[wv] = m1; sm2[wv] = m2;
                svscan[wv] = vsh[PAD_IDX(j1)];   // price the bid is based on
            }
        }
        __syncthreads();
        if (tid == 0) {
            int qt2 = qstate[1];
            for (int s = 0; s < take; ++s) {
                int i = srow[s], j1 = scol[s];
                int pj1 = PAD_IDX(j1);
                if (vsh[pj1] == svscan[s]) {
                    float delta = fmaxf(sm2[s] - sm1[s], AUCTION_EPS);
                    int old = pcol[pj1];
                    vsh[pj1]  = svscan[s] - delta;
                    pcol[pj1] = i;
                    uu[pj1]   = sm1[s] + delta;   // matched edge exactly tight
                    urow[i]   = sm1[s] + delta;
                    done[i]   = 1;
                    if (old >= 0) { qbuf[qt2 & 1023] = old; ++qt2; done[old] = 0; }
                } else {
                    qbuf[qt2 & 1023] = i; ++qt2;  // stale price -> rescan
                }
            }
            qstate[0] = qstate[0] + take;
            qstate[1] = qt2;
        }
        __syncthreads();
    }

    // ---- Phase C: exact shortest augmenting path for leftovers (wave 0)
    float v[16], d[16];
    if (tid < 64) {
        #pragma unroll
        for (int k = 0; k < 16; ++k) v[k] = vsh[PAD_IDX(base + k)];
    }
    __syncthreads();

    for (int i = 0; i < NTGT; ++i) {
        if (done[i]) continue;                 // uniform LDS read
        float ui = urow[i];
        float Df = 0.f;
        int jf = -1;
        if (tid < 64) {
            const float4* row4 = reinterpret_cast<const float4*>(C + (size_t)i * NSP + base);
            #pragma unroll
            for (int q = 0; q < 4; ++q) {
                float4 c4 = row4[q];
                d[4*q+0] = c4.x - ui - v[4*q+0];
                d[4*q+1] = c4.y - ui - v[4*q+1];
                d[4*q+2] = c4.z - ui - v[4*q+2];
                d[4*q+3] = c4.w - ui - v[4*q+3];
            }
            #pragma unroll
            for (int k = 0; k < 16; ++k) way[PAD_IDX(base + k)] = -1;
            unsigned int used = 0;

            for (int it = 0; it < NTGT + 3; ++it) {
                float lmin = 1e38f;
                #pragma unroll
                for (int k = 0; k < 16; ++k) {
                    float val = ((used >> k) & 1u) ? 1e38f : d[k];
                    lmin = fminf(lmin, val);
                }
                float wmin = lmin;
                #pragma unroll
                for (int off = 32; off >= 1; off >>= 1) wmin = fminf(wmin, __shfl_xor(wmin, off));
                unsigned long long msk = __ballot(lmin == wmin);
                int src = __ffsll(msk) - 1;
                int myk = -1;
                #pragma unroll
                for (int k = 15; k >= 0; --k)
                    if (!((used >> k) & 1u) && d[k] == wmin) myk = k;
                int j0 = __shfl(base + myk, src);
                if (j0 < 0) break;                    // NaN safety net
                int pj0 = pcol[PAD_IDX(j0)];
                if (pj0 < 0) { Df = wmin; jf = j0; break; }   // free column
                if ((j0 >> 4) == lane) used |= 1u << (j0 & 15);
                float uref = uu[PAD_IDX(j0)];
                float sft  = wmin - uref;
                const float4* rr = reinterpret_cast<const float4*>(C + (size_t)pj0 * NSP + base);
                float cr[16];
                #pragma unroll
                for (int q = 0; q < 4; ++q) {
                    float4 c4 = rr[q];
                    cr[4*q+0] = c4.x; cr[4*q+1] = c4.y; cr[4*q+2] = c4.z; cr[4*q+3] = c4.w;
                }
                #pragma unroll
                for (int k = 0; k < 16; ++k) {
                    float cand = sft + cr[k] - v[k];
                    bool upd = (cand < d[k]) && !((used >> k) & 1u);
                    if (upd) { d[k] = cand; way[PAD_IDX(base + k)] = j0; }
                }
            }

            // dual updates: v -= (Df - d), u[row] += (Df - d) on scanned cols
            if (jf >= 0) {
                #pragma unroll
                for (int k = 0; k < 16; ++k) {
                    if ((used >> k) & 1u) {
                        float diff = Df - d[k];
                        v[k] -= diff;
                        uu[PAD_IDX(base + k)] += diff;
                    }
                }
            }
        }
        __syncthreads();
        if (tid == 0 && jf >= 0) {            // tid 0 is lane 0 of wave 0
            int j = jf;
            for (int g = 0; g < NSP; ++g) {
                int jp = way[PAD_IDX(j)];
                if (jp < 0) { pcol[PAD_IDX(j)] = i; uu[PAD_IDX(j)] = ui + Df; break; }
                pcol[PAD_IDX(j)] = pcol[PAD_IDX(jp)];
                uu[PAD_IDX(j)]   = uu[PAD_IDX(jp)];
                j = jp;
            }
            done[i] = 1;
        }
        __syncthreads();
    }

    // ---- mean of matched costs (wave 0)
    if (tid < 64) {
        float acc = 0.f;
        #pragma unroll
        for (int k = 0; k < 16; ++k) {
            int j = base + k;
            if (j < NSRC) {
                int r = pcol[PAD_IDX(j)];
                if (r >= 0) acc += C[(size_t)r * NSP + j];
            }
        }
        #pragma unroll
        for (int off = 32; off >= 1; off >>= 1) acc += __shfl_xor(acc, off);
        if (lane == 0) out[b] = acc * (1.0f / NTGT);
    }
}

extern "C" void kernel_launch(void* const* d_in, const int* in_sizes, int n_in,
                              void* d_out, int out_size, void* d_ws, size_t ws_size,
                              hipStream_t stream) {
    const float* logits = (const float*)d_in[0];   // (32,1000,256) f32
    const int*   tcls   = (const int*)  d_in[1];   // (32,100) i32
    const float* sbox   = (const float*)d_in[2];   // (32,1000,4) f32
    const float* tbox   = (const float*)d_in[3];   // (32,100,4) f32
    float* out = (float*)d_out;                    // (32,) f32

    float* lse    = (float*)d_ws;                   // 32768 floats
    float* cost   = lse + 32768;                    // 32*100*1024 floats (~13.1 MB)
    float* urow_g = cost + (size_t)NB * NTGT * NSP; // 3200 floats
    int*   jmin_g = (int*)(urow_g + NB * NTGT);     // 3200 ints
    float* m2_g   = (float*)(jmin_g + NB * NTGT);   // 3200 floats

    lse_kernel <<<1000,      256, 0, stream>>>(logits, lse);
    cost_kernel<<<NB * NTGT, 256, 0, stream>>>(logits, tcls, sbox, tbox, lse, cost,
                                               urow_g, jmin_g, m2_g);
    lsa_kernel <<<NB,        256, 0, stream>>>(cost, urow_g, jmin_g, m2_g, out);
}

// Round 8
// 127.757 us; speedup vs baseline: 1.2039x; 1.0067x over previous
//
#include <hip/hip_runtime.h>
#include <math.h>

#define NSRC 1000
#define NTGT 100
#define NCLS 256
#define NB   32
#define NSP  1024                 // padded column count for LSA
#define PAD_IDX(j) ((j) + ((j) >> 4))
#define LDSN (NSP + (NSP >> 4))   // 1088 padded LDS entries
#define AUCTION_EPS 0.01f
#define NWAVES 8
#define ROUND_CAP 160

// R6 post-mortem: column reduction (v[j]=colmin>0) is INVALID for rectangular
// LAP (dual needs v<=0, v<0 only on matched cols). v starts 0, only decreases.
// R7 post-mortem: harness poison-fill of d_ws (256 MiB @ 6.2 TB/s = 43.5 us)
// dominates the dispatch list — unavoidable floor. Controllable: lse+cost+lsa.

// ---------------- per-(b,s) logsumexp over 256 classes ----------------------
__global__ __launch_bounds__(256) void lse_kernel(const float* __restrict__ logits,
                                                  float* __restrict__ lse) {
    int wid  = threadIdx.x >> 6;
    int lane = threadIdx.x & 63;
    int row0 = blockIdx.x * 32 + wid * 8;
    #pragma unroll 2
    for (int r = 0; r < 8; ++r) {
        int row = row0 + r;
        float4 v4 = reinterpret_cast<const float4*>(logits + (size_t)row * NCLS)[lane];
        float m = fmaxf(fmaxf(v4.x, v4.y), fmaxf(v4.z, v4.w));
        #pragma unroll
        for (int off = 32; off >= 1; off >>= 1) m = fmaxf(m, __shfl_xor(m, off));
        float s = expf(v4.x - m) + expf(v4.y - m) + expf(v4.z - m) + expf(v4.w - m);
        #pragma unroll
        for (int off = 32; off >= 1; off >>= 1) s += __shfl_xor(s, off);
        if (lane == 0) lse[row] = m + logf(s);
    }
}

// ---------------- transposed cost row + fused top-2 row reduction -----------
// One block per (b,t); b = blockIdx&31 (XCD locality).
__global__ __launch_bounds__(256) void cost_kernel(const float* __restrict__ logits,
                                                   const int*   __restrict__ tcls,
                                                   const float* __restrict__ sbox,
                                                   const float* __restrict__ tbox,
                                                   const float* __restrict__ lse,
                                                   float*       __restrict__ cost,
                                                   float*       __restrict__ urow_g,
                                                   int*         __restrict__ jmin_g,
                                                   float*       __restrict__ m2_g) {
    int b  = blockIdx.x & 31;
    int t  = blockIdx.x >> 5;
    int bt = b * NTGT + t;
    int cls = tcls[bt];
    float4 tb = reinterpret_cast<const float4*>(tbox)[bt];
    float area_t = (tb.z - tb.x) * (tb.w - tb.y);
    float* crow = cost + (size_t)bt * NSP;
    float m1 = 1e38f, m2 = 1e38f; int mi = 0x7fffffff;
    for (int s = threadIdx.x; s < NSP; s += 256) {
        if (s >= NSRC) { crow[s] = 1e30f; continue; }
        int gs = b * NSRC + s;
        float4 sb = reinterpret_cast<const float4*>(sbox)[gs];
        float ce = lse[gs] - logits[(size_t)gs * NCLS + cls];
        float ix1 = fmaxf(sb.x, tb.x), iy1 = fmaxf(sb.y, tb.y);
        float ix2 = fminf(sb.z, tb.z), iy2 = fminf(sb.w, tb.w);
        float inter = fmaxf(ix2 - ix1, 0.f) * fmaxf(iy2 - iy1, 0.f);
        float area_s = (sb.z - sb.x) * (sb.w - sb.y);
        float uni = area_s + area_t - inter;
        float iou = inter / uni;
        float cx1 = fminf(sb.x, tb.x), cy1 = fminf(sb.y, tb.y);
        float cx2 = fmaxf(sb.z, tb.z), cy2 = fmaxf(sb.w, tb.w);
        float carea = (cx2 - cx1) * (cy2 - cy1);
        float giou = iou - (carea - uni) / carea;
        float l1 = 0.25f * (fabsf(sb.x - tb.x) + fabsf(sb.y - tb.y) +
                            fabsf(sb.z - tb.z) + fabsf(sb.w - tb.w));
        float c = ce + 10.0f * (1.0f - giou) + l1;
        crow[s] = c;
        if (c < m1) { m2 = m1; m1 = c; mi = s; }
        else if (c < m2) m2 = c;
    }
    #pragma unroll
    for (int off = 32; off >= 1; off >>= 1) {
        float om1 = __shfl_xor(m1, off);
        float om2 = __shfl_xor(m2, off);
        int   oi  = __shfl_xor(mi, off);
        bool take = (om1 < m1) || (om1 == m1 && oi < mi);
        float lose = take ? m1 : om1;
        m1 = take ? om1 : m1;
        mi = take ? oi  : mi;
        m2 = fminf(fminf(m2, om2), lose);
    }
    __shared__ float smin[4], smin2[4];
    __shared__ int   sidx[4];
    int wid = threadIdx.x >> 6, lane = threadIdx.x & 63;
    if (lane == 0) { smin[wid] = m1; smin2[wid] = m2; sidx[wid] = mi; }
    __syncthreads();
    if (threadIdx.x == 0) {
        #pragma unroll
        for (int w = 1; w < 4; ++w) {
            float om1 = smin[w], om2 = smin2[w]; int oi = sidx[w];
            bool take = (om1 < m1) || (om1 == m1 && oi < mi);
            float lose = take ? m1 : om1;
            m1 = take ? om1 : m1;
            mi = take ? oi  : mi;
            m2 = fminf(fminf(m2, om2), lose);
        }
        urow_g[bt] = m1;
        jmin_g[bt] = mi;
        m2_g[bt]   = m2;
    }
}

// ---------------- JV: claim -> eps-auction with bid repair -> Dijkstra ------
// One block (512 threads = 8 waves) per batch.
// Bid-repair principle: prices only drop => reduced costs only rise. A stored
// bid (bm1,bm2,bj,bv) is repairable: m1p = bm1 + (bv - v[bj]_now) is the
// EXACT current reduced cost at bj, and bm2 is still a valid lower bound on
// all other columns. If m1p <= bm2, commit with zero rescans.
__global__ __launch_bounds__(512) void lsa_kernel(const float* __restrict__ cost,
                                                  const float* __restrict__ urow_g,
                                                  const int*   __restrict__ jmin_g,
                                                  const float* __restrict__ m2_g,
                                                  float* __restrict__ out) {
    int b    = blockIdx.x;
    int tid  = threadIdx.x;
    int wv   = tid >> 6;
    int lane = tid & 63;
    const float* C = cost + (size_t)b * NTGT * NSP;
    __shared__ int   way[LDSN];     // pred chain; reused as claim[] first
    __shared__ int   pcol[LDSN];    // col -> assigned row
    __shared__ float uu[LDSN];      // col -> u of its assigned row
    __shared__ float vsh[LDSN];     // column duals v (<= 0)
    __shared__ float urow[NTGT];    // row dual u
    __shared__ int   done[NTGT];    // currently assigned?
    __shared__ float bm1[NTGT];     // stored bid: best reduced cost at scan
    __shared__ float bm2[NTGT];     //             second-best (lower bound)
    __shared__ int   bj [NTGT];     //             best column
    __shared__ float bv [NTGT];     //             v[bj] at scan time
    __shared__ int   qbuf[1024];    // ring buffer of free rows
    __shared__ int   qstate[2];     // qh, qt
    __shared__ int   srow[NWAVES];

    for (int t = tid; t < LDSN; t += 512) {
        pcol[t] = -1; uu[t] = 0.f; vsh[t] = 0.f; way[t] = 0x7fffffff;
    }
    for (int t = tid; t < NTGT; t += 512) {
        float m1 = urow_g[b * NTGT + t];
        urow[t] = m1;
        bm1[t]  = m1;
        bm2[t]  = m2_g[b * NTGT + t];
        bj[t]   = jmin_g[b * NTGT + t];
        bv[t]   = 0.f;
    }
    if (tid == 0) { qstate[0] = 0; qstate[1] = 0; }
    __syncthreads();

    // ---- Phase A: claim argmin columns (lowest row index wins)
    for (int r = tid; r < NTGT; r += 512) atomicMin(&way[PAD_IDX(bj[r])], r);
    __syncthreads();
    for (int r = tid; r < NTGT; r += 512) {
        int j = bj[r];
        int w = (way[PAD_IDX(j)] == r) ? 1 : 0;
        done[r] = w;
        if (w) { pcol[PAD_IDX(j)] = r; uu[PAD_IDX(j)] = urow[r]; }
    }
    __syncthreads();

    // ---- queue build: wave 0 ballot compaction of Phase-A losers
    if (tid < 64) {
        int qt = 0;
        #pragma unroll
        for (int r0 = 0; r0 < 128; r0 += 64) {
            int r = r0 + lane;
            bool act = (r < NTGT) && !done[r];
            unsigned long long mask = __ballot(act);
            if (act) qbuf[qt + __popcll(mask & ((1ull << lane) - 1ull))] = r;
            qt += __popcll(mask);
        }
        if (lane == 0) qstate[1] = qt;
    }
    __syncthreads();

    int base = lane * 16;

    // ---- Phase B: rounds of (repair-check / rescan) + serial commit
    for (int round = 0; round < ROUND_CAP; ++round) {
        int qh = qstate[0], qt = qstate[1];   // uniform after barrier
        int navail = qt - qh;
        if (navail <= 0) break;
        int take = navail < NWAVES ? navail : NWAVES;
        if (wv < take) {
            int i = qbuf[(qh + wv) & 1023];   // wave-uniform
            if (lane == 0) srow[wv] = i;
            // repairable? exact current reduced cost at stored best column
            float m1p = bm1[i] + (bv[i] - vsh[PAD_IDX(bj[i])]);
            if (m1p > bm2[i]) {
                // full rescan against current prices; store fresh bid
                const float4* row4 = reinterpret_cast<const float4*>(C + (size_t)i * NSP + base);
                float m1 = 1e38f, m2 = 1e38f; int j1 = 0x7fffffff;
                #pragma unroll
                for (int q = 0; q < 4; ++q) {
                    float4 c4 = row4[q];
                    float vals[4];
                    vals[0] = c4.x - vsh[PAD_IDX(base + 4*q + 0)];
                    vals[1] = c4.y - vsh[PAD_IDX(base + 4*q + 1)];
                    vals[2] = c4.z - vsh[PAD_IDX(base + 4*q + 2)];
                    vals[3] = c4.w - vsh[PAD_IDX(base + 4*q + 3)];
                    #pragma unroll
                    for (int e = 0; e < 4; ++e) {
                        float val = vals[e];
                        if (val < m1) { m2 = m1; m1 = val; j1 = base + 4*q + e; }
                        else m2 = fminf(m2, val);
                    }
                }
                #pragma unroll
                for (int off = 32; off >= 1; off >>= 1) {
                    float om1 = __shfl_xor(m1, off);
                    float om2 = __shfl_xor(m2, off);
                    int   oj1 = __shfl_xor(j1, off);
                    bool tk = (om1 < m1) || (om1 == m1 && oj1 < j1);
                    float lose = tk ? m1 : om1;
                    m1 = tk ? om1 : m1;
                    j1 = tk ? oj1 : j1;
                    m2 = fminf(fminf(m2, om2), lose);
                }
                if (lane == 0) {
                    bm1[i] = m1; bm2[i] = m2; bj[i] = j1;
                    bv[i]  = vsh[PAD_IDX(j1)];
                }
            }
        }
        __syncthreads();
        if (tid == 0) {
            int qt2 = qstate[1];
            for (int s = 0; s < take; ++s) {
                int i  = srow[s];
                int j1 = bj[i];
                int pj1 = PAD_IDX(j1);
                float vnow = vsh[pj1];
                float m1p  = bm1[i] + (bv[i] - vnow);   // exact current rc at j1
                if (m1p <= bm2[i]) {
                    float delta = fmaxf(bm2[i] - m1p, AUCTION_EPS);
                    int old = pcol[pj1];
                    vsh[pj1]  = vnow - delta;
                    pcol[pj1] = i;
                    uu[pj1]   = m1p + delta;            // matched edge tight
                    urow[i]   = m1p + delta;
                    done[i]   = 1;
                    if (old >= 0) { qbuf[qt2 & 1023] = old; ++qt2; done[old] = 0; }
                } else {
                    qbuf[qt2 & 1023] = i; ++qt2;        // rescan next round
                }
            }
            qstate[0] = qstate[0] + take;
            qstate[1] = qt2;
        }
        __syncthreads();
    }

    // ---- Phase C: exact shortest augmenting path for leftovers (wave 0)
    float v[16], d[16];
    if (tid < 64) {
        #pragma unroll
        for (int k = 0; k < 16; ++k) v[k] = vsh[PAD_IDX(base + k)];
    }
    __syncthreads();

    for (int i = 0; i < NTGT; ++i) {
        if (done[i]) continue;                 // uniform LDS read
        float ui = urow[i];
        float Df = 0.f;
        int jf = -1;
        if (tid < 64) {
            const float4* row4 = reinterpret_cast<const float4*>(C + (size_t)i * NSP + base);
            #pragma unroll
            for (int q = 0; q < 4; ++q) {
                float4 c4 = row4[q];
                d[4*q+0] = c4.x - ui - v[4*q+0];
                d[4*q+1] = c4.y - ui - v[4*q+1];
                d[4*q+2] = c4.z - ui - v[4*q+2];
                d[4*q+3] = c4.w - ui - v[4*q+3];
            }
            #pragma unroll
            for (int k = 0; k < 16; ++k) way[PAD_IDX(base + k)] = -1;
            unsigned int used = 0;

            for (int it = 0; it < NTGT + 3; ++it) {
                float lmin = 1e38f;
                #pragma unroll
                for (int k = 0; k < 16; ++k) {
                    float val = ((used >> k) & 1u) ? 1e38f : d[k];
                    lmin = fminf(lmin, val);
                }
                float wmin = lmin;
                #pragma unroll
                for (int off = 32; off >= 1; off >>= 1) wmin = fminf(wmin, __shfl_xor(wmin, off));
                unsigned long long msk = __ballot(lmin == wmin);
                int src = __ffsll(msk) - 1;
                int myk = -1;
                #pragma unroll
                for (int k = 15; k >= 0; --k)
                    if (!((used >> k) & 1u) && d[k] == wmin) myk = k;
                int j0 = __shfl(base + myk, src);
                if (j0 < 0) break;                    // NaN safety net
                int pj0 = pcol[PAD_IDX(j0)];
                if (pj0 < 0) { Df = wmin; jf = j0; break; }   // free column
                if ((j0 >> 4) == lane) used |= 1u << (j0 & 15);
                float uref = uu[PAD_IDX(j0)];
                float sft  = wmin - uref;
                const float4* rr = reinterpret_cast<const float4*>(C + (size_t)pj0 * NSP + base);
                float cr[16];
                #pragma unroll
                for (int q = 0; q < 4; ++q) {
                    float4 c4 = rr[q];
                    cr[4*q+0] = c4.x; cr[4*q+1] = c4.y; cr[4*q+2] = c4.z; cr[4*q+3] = c4.w;
                }
                #pragma unroll
                for (int k = 0; k < 16; ++k) {
                    float cand = sft + cr[k] - v[k];
                    bool upd = (cand < d[k]) && !((used >> k) & 1u);
                    if (upd) { d[k] = cand; way[PAD_IDX(base + k)] = j0; }
                }
            }

            // dual updates: v -= (Df - d), u[row] += (Df - d) on scanned cols
            if (jf >= 0) {
                #pragma unroll
                for (int k = 0; k < 16; ++k) {
                    if ((used >> k) & 1u) {
                        float diff = Df - d[k];
                        v[k] -= diff;
                        uu[PAD_IDX(base + k)] += diff;
                    }
                }
            }
        }
        __syncthreads();
        if (tid == 0 && jf >= 0) {            // tid 0 is lane 0 of wave 0
            int j = jf;
            for (int g = 0; g < NSP; ++g) {
                int jp = way[PAD_IDX(j)];
                if (jp < 0) { pcol[PAD_IDX(j)] = i; uu[PAD_IDX(j)] = ui + Df; break; }
                pcol[PAD_IDX(j)] = pcol[PAD_IDX(jp)];
                uu[PAD_IDX(j)]   = uu[PAD_IDX(jp)];
                j = jp;
            }
            done[i] = 1;
        }
        __syncthreads();
    }

    // ---- mean of matched costs (wave 0)
    if (tid < 64) {
        float acc = 0.f;
        #pragma unroll
        for (int k = 0; k < 16; ++k) {
            int j = base + k;
            if (j < NSRC) {
                int r = pcol[PAD_IDX(j)];
                if (r >= 0) acc += C[(size_t)r * NSP + j];
            }
        }
        #pragma unroll
        for (int off = 32; off >= 1; off >>= 1) acc += __shfl_xor(acc, off);
        if (lane == 0) out[b] = acc * (1.0f / NTGT);
    }
}

extern "C" void kernel_launch(void* const* d_in, const int* in_sizes, int n_in,
                              void* d_out, int out_size, void* d_ws, size_t ws_size,
                              hipStream_t stream) {
    const float* logits = (const float*)d_in[0];   // (32,1000,256) f32
    const int*   tcls   = (const int*)  d_in[1];   // (32,100) i32
    const float* sbox   = (const float*)d_in[2];   // (32,1000,4) f32
    const float* tbox   = (const float*)d_in[3];   // (32,100,4) f32
    float* out = (float*)d_out;                    // (32,) f32

    float* lse    = (float*)d_ws;                   // 32768 floats
    float* cost   = lse + 32768;                    // 32*100*1024 floats (~13.1 MB)
    float* urow_g = cost + (size_t)NB * NTGT * NSP; // 3200 floats
    int*   jmin_g = (int*)(urow_g + NB * NTGT);     // 3200 ints
    float* m2_g   = (float*)(jmin_g + NB * NTGT);   // 3200 floats

    lse_kernel <<<1000,      256, 0, stream>>>(logits, lse);
    cost_kernel<<<NB * NTGT, 256, 0, stream>>>(logits, tcls, sbox, tbox, lse, cost,
                                               urow_g, jmin_g, m2_g);
    lsa_kernel <<<NB,        512, 0, stream>>>(cost, urow_g, jmin_g, m2_g, out);
}

// Round 9
// 126.611 us; speedup vs baseline: 1.2148x; 1.0090x over previous
//
#include <hip/hip_runtime.h>
#include <math.h>

#define NSRC 1000
#define NTGT 100
#define NCLS 256
#define NB   32
#define NSP  1024                 // padded column count for LSA
#define PAD_IDX(j) ((j) + ((j) >> 4))
#define LDSN (NSP + (NSP >> 4))   // 1088 padded LDS entries
#define AUCTION_EPS 0.04f
#define NWAVES 8
#define ROUND_CAP 96

// R6 post-mortem: column reduction (v[j]=colmin>0) is INVALID for rectangular
// LAP (dual needs v<=0, v<0 only on matched cols). v starts 0, only decreases.
// R7 post-mortem: harness poison-fill of d_ws (256 MiB @ 6.2 TB/s = 43.5 us)
// plus input restore/gaps is a fixed ~100 us floor. Controllable: lse+cost+lsa.
// R8 post-mortem: lsa ~= 28 us; eps=0.01 price wars + Dijkstra row-load latency
// are the two remaining serial terms.

// ---------------- per-(b,s) logsumexp over 256 classes ----------------------
__global__ __launch_bounds__(256) void lse_kernel(const float* __restrict__ logits,
                                                  float* __restrict__ lse) {
    int wid  = threadIdx.x >> 6;
    int lane = threadIdx.x & 63;
    int row0 = blockIdx.x * 32 + wid * 8;
    #pragma unroll 2
    for (int r = 0; r < 8; ++r) {
        int row = row0 + r;
        float4 v4 = reinterpret_cast<const float4*>(logits + (size_t)row * NCLS)[lane];
        float m = fmaxf(fmaxf(v4.x, v4.y), fmaxf(v4.z, v4.w));
        #pragma unroll
        for (int off = 32; off >= 1; off >>= 1) m = fmaxf(m, __shfl_xor(m, off));
        float s = expf(v4.x - m) + expf(v4.y - m) + expf(v4.z - m) + expf(v4.w - m);
        #pragma unroll
        for (int off = 32; off >= 1; off >>= 1) s += __shfl_xor(s, off);
        if (lane == 0) lse[row] = m + logf(s);
    }
}

// ---------------- transposed cost row + fused top-2 row reduction -----------
// One block per (b,t); b = blockIdx&31 (XCD locality).
__global__ __launch_bounds__(256) void cost_kernel(const float* __restrict__ logits,
                                                   const int*   __restrict__ tcls,
                                                   const float* __restrict__ sbox,
                                                   const float* __restrict__ tbox,
                                                   const float* __restrict__ lse,
                                                   float*       __restrict__ cost,
                                                   float*       __restrict__ urow_g,
                                                   int*         __restrict__ jmin_g,
                                                   float*       __restrict__ m2_g) {
    int b  = blockIdx.x & 31;
    int t  = blockIdx.x >> 5;
    int bt = b * NTGT + t;
    int cls = tcls[bt];
    float4 tb = reinterpret_cast<const float4*>(tbox)[bt];
    float area_t = (tb.z - tb.x) * (tb.w - tb.y);
    float* crow = cost + (size_t)bt * NSP;
    float m1 = 1e38f, m2 = 1e38f; int mi = 0x7fffffff;
    for (int s = threadIdx.x; s < NSP; s += 256) {
        if (s >= NSRC) { crow[s] = 1e30f; continue; }
        int gs = b * NSRC + s;
        float4 sb = reinterpret_cast<const float4*>(sbox)[gs];
        float ce = lse[gs] - logits[(size_t)gs * NCLS + cls];
        float ix1 = fmaxf(sb.x, tb.x), iy1 = fmaxf(sb.y, tb.y);
        float ix2 = fminf(sb.z, tb.z), iy2 = fminf(sb.w, tb.w);
        float inter = fmaxf(ix2 - ix1, 0.f) * fmaxf(iy2 - iy1, 0.f);
        float area_s = (sb.z - sb.x) * (sb.w - sb.y);
        float uni = area_s + area_t - inter;
        float iou = inter / uni;
        float cx1 = fminf(sb.x, tb.x), cy1 = fminf(sb.y, tb.y);
        float cx2 = fmaxf(sb.z, tb.z), cy2 = fmaxf(sb.w, tb.w);
        float carea = (cx2 - cx1) * (cy2 - cy1);
        float giou = iou - (carea - uni) / carea;
        float l1 = 0.25f * (fabsf(sb.x - tb.x) + fabsf(sb.y - tb.y) +
                            fabsf(sb.z - tb.z) + fabsf(sb.w - tb.w));
        float c = ce + 10.0f * (1.0f - giou) + l1;
        crow[s] = c;
        if (c < m1) { m2 = m1; m1 = c; mi = s; }
        else if (c < m2) m2 = c;
    }
    #pragma unroll
    for (int off = 32; off >= 1; off >>= 1) {
        float om1 = __shfl_xor(m1, off);
        float om2 = __shfl_xor(m2, off);
        int   oi  = __shfl_xor(mi, off);
        bool take = (om1 < m1) || (om1 == m1 && oi < mi);
        float lose = take ? m1 : om1;
        m1 = take ? om1 : m1;
        mi = take ? oi  : mi;
        m2 = fminf(fminf(m2, om2), lose);
    }
    __shared__ float smin[4], smin2[4];
    __shared__ int   sidx[4];
    int wid = threadIdx.x >> 6, lane = threadIdx.x & 63;
    if (lane == 0) { smin[wid] = m1; smin2[wid] = m2; sidx[wid] = mi; }
    __syncthreads();
    if (threadIdx.x == 0) {
        #pragma unroll
        for (int w = 1; w < 4; ++w) {
            float om1 = smin[w], om2 = smin2[w]; int oi = sidx[w];
            bool take = (om1 < m1) || (om1 == m1 && oi < mi);
            float lose = take ? m1 : om1;
            m1 = take ? om1 : m1;
            mi = take ? oi  : mi;
            m2 = fminf(fminf(m2, om2), lose);
        }
        urow_g[bt] = m1;
        jmin_g[bt] = mi;
        m2_g[bt]   = m2;
    }
}

// ---------------- JV: claim -> eps-auction with bid repair -> Dijkstra ------
// One block (512 threads = 8 waves) per batch. Phase C uses an index-carrying
// top-2 butterfly and speculative prefetch of the runner-up column's owner row
// (pcol is immutable during one Dijkstra, so the prefetch is always coherent).
__global__ __launch_bounds__(512) void lsa_kernel(const float* __restrict__ cost,
                                                  const float* __restrict__ urow_g,
                                                  const int*   __restrict__ jmin_g,
                                                  const float* __restrict__ m2_g,
                                                  float* __restrict__ out) {
    int b    = blockIdx.x;
    int tid  = threadIdx.x;
    int wv   = tid >> 6;
    int lane = tid & 63;
    const float* C = cost + (size_t)b * NTGT * NSP;
    __shared__ int   way[LDSN];     // pred chain; reused as claim[] first
    __shared__ int   pcol[LDSN];    // col -> assigned row
    __shared__ float uu[LDSN];      // col -> u of its assigned row
    __shared__ float vsh[LDSN];     // column duals v (<= 0)
    __shared__ float urow[NTGT];    // row dual u
    __shared__ int   done[NTGT];    // currently assigned?
    __shared__ float bm1[NTGT];     // stored bid: best reduced cost at scan
    __shared__ float bm2[NTGT];     //             second-best (lower bound)
    __shared__ int   bj [NTGT];     //             best column
    __shared__ float bv [NTGT];     //             v[bj] at scan time
    __shared__ int   qbuf[1024];    // ring buffer of free rows
    __shared__ int   qstate[2];     // qh, qt
    __shared__ int   srow[NWAVES];

    for (int t = tid; t < LDSN; t += 512) {
        pcol[t] = -1; uu[t] = 0.f; vsh[t] = 0.f; way[t] = 0x7fffffff;
    }
    for (int t = tid; t < NTGT; t += 512) {
        float m1 = urow_g[b * NTGT + t];
        urow[t] = m1;
        bm1[t]  = m1;
        bm2[t]  = m2_g[b * NTGT + t];
        bj[t]   = jmin_g[b * NTGT + t];
        bv[t]   = 0.f;
    }
    if (tid == 0) { qstate[0] = 0; qstate[1] = 0; }
    __syncthreads();

    // ---- Phase A: claim argmin columns (lowest row index wins)
    for (int r = tid; r < NTGT; r += 512) atomicMin(&way[PAD_IDX(bj[r])], r);
    __syncthreads();
    for (int r = tid; r < NTGT; r += 512) {
        int j = bj[r];
        int w = (way[PAD_IDX(j)] == r) ? 1 : 0;
        done[r] = w;
        if (w) { pcol[PAD_IDX(j)] = r; uu[PAD_IDX(j)] = urow[r]; }
    }
    __syncthreads();

    // ---- queue build: wave 0 ballot compaction of Phase-A losers
    if (tid < 64) {
        int qt = 0;
        #pragma unroll
        for (int r0 = 0; r0 < 128; r0 += 64) {
            int r = r0 + lane;
            bool act = (r < NTGT) && !done[r];
            unsigned long long mask = __ballot(act);
            if (act) qbuf[qt + __popcll(mask & ((1ull << lane) - 1ull))] = r;
            qt += __popcll(mask);
        }
        if (lane == 0) qstate[1] = qt;
    }
    __syncthreads();

    int base = lane * 16;

    // ---- Phase B: rounds of (repair-check / rescan) + serial commit
    for (int round = 0; round < ROUND_CAP; ++round) {
        int qh = qstate[0], qt = qstate[1];   // uniform after barrier
        int navail = qt - qh;
        if (navail <= 0) break;
        int take = navail < NWAVES ? navail : NWAVES;
        if (wv < take) {
            int i = qbuf[(qh + wv) & 1023];   // wave-uniform
            if (lane == 0) srow[wv] = i;
            // repairable? exact current reduced cost at stored best column
            float m1p = bm1[i] + (bv[i] - vsh[PAD_IDX(bj[i])]);
            if (m1p > bm2[i]) {
                // full rescan against current prices; store fresh bid
                const float4* row4 = reinterpret_cast<const float4*>(C + (size_t)i * NSP + base);
                float m1 = 1e38f, m2 = 1e38f; int j1 = 0x7fffffff;
                #pragma unroll
                for (int q = 0; q < 4; ++q) {
                    float4 c4 = row4[q];
                    float vals[4];
                    vals[0] = c4.x - vsh[PAD_IDX(base + 4*q + 0)];
                    vals[1] = c4.y - vsh[PAD_IDX(base + 4*q + 1)];
                    vals[2] = c4.z - vsh[PAD_IDX(base + 4*q + 2)];
                    vals[3] = c4.w - vsh[PAD_IDX(base + 4*q + 3)];
                    #pragma unroll
                    for (int e = 0; e < 4; ++e) {
                        float val = vals[e];
                        if (val < m1) { m2 = m1; m1 = val; j1 = base + 4*q + e; }
                        else m2 = fminf(m2, val);
                    }
                }
                #pragma unroll
                for (int off = 32; off >= 1; off >>= 1) {
                    float om1 = __shfl_xor(m1, off);
                    float om2 = __shfl_xor(m2, off);
                    int   oj1 = __shfl_xor(j1, off);
                    bool tk = (om1 < m1) || (om1 == m1 && oj1 < j1);
                    float lose = tk ? m1 : om1;
                    m1 = tk ? om1 : m1;
                    j1 = tk ? oj1 : j1;
                    m2 = fminf(fminf(m2, om2), lose);
                }
                if (lane == 0) {
                    bm1[i] = m1; bm2[i] = m2; bj[i] = j1;
                    bv[i]  = vsh[PAD_IDX(j1)];
                }
            }
        }
        __syncthreads();
        if (tid == 0) {
            int qt2 = qstate[1];
            for (int s = 0; s < take; ++s) {
                int i  = srow[s];
                int j1 = bj[i];
                int pj1 = PAD_IDX(j1);
                float vnow = vsh[pj1];
                float m1p  = bm1[i] + (bv[i] - vnow);   // exact current rc at j1
                if (m1p <= bm2[i]) {
                    float delta = fmaxf(bm2[i] - m1p, AUCTION_EPS);
                    int old = pcol[pj1];
                    vsh[pj1]  = vnow - delta;
                    pcol[pj1] = i;
                    uu[pj1]   = m1p + delta;            // matched edge tight
                    urow[i]   = m1p + delta;
                    done[i]   = 1;
                    if (old >= 0) { qbuf[qt2 & 1023] = old; ++qt2; done[old] = 0; }
                } else {
                    qbuf[qt2 & 1023] = i; ++qt2;        // rescan next round
                }
            }
            qstate[0] = qstate[0] + take;
            qstate[1] = qt2;
        }
        __syncthreads();
    }

    // ---- Phase C: exact shortest augmenting path for leftovers (wave 0)
    float v[16], d[16];
    if (tid < 64) {
        #pragma unroll
        for (int k = 0; k < 16; ++k) v[k] = vsh[PAD_IDX(base + k)];
    }
    __syncthreads();

    for (int i = 0; i < NTGT; ++i) {
        if (done[i]) continue;                 // uniform LDS read
        float ui = urow[i];
        float Df = 0.f;
        int jf = -1;
        if (tid < 64) {
            const float4* row4 = reinterpret_cast<const float4*>(C + (size_t)i * NSP + base);
            #pragma unroll
            for (int q = 0; q < 4; ++q) {
                float4 c4 = row4[q];
                d[4*q+0] = c4.x - ui - v[4*q+0];
                d[4*q+1] = c4.y - ui - v[4*q+1];
                d[4*q+2] = c4.z - ui - v[4*q+2];
                d[4*q+3] = c4.w - ui - v[4*q+3];
            }
            #pragma unroll
            for (int k = 0; k < 16; ++k) way[PAD_IDX(base + k)] = -1;
            unsigned int used = 0;
            int   pf_j = -1;                    // prefetched column (owner row data)
            float pfr[16];

            for (int it = 0; it < NTGT + 3; ++it) {
                // per-lane top-2 (value,index)
                float l1 = 1e38f, l2 = 1e38f;
                int   i1 = 0x7fffffff, i2 = 0x7fffffff;
                #pragma unroll
                for (int k = 0; k < 16; ++k) {
                    float val = ((used >> k) & 1u) ? 1e38f : d[k];
                    int idx = base + k;
                    if (val < l1) { l2 = l1; i2 = i1; l1 = val; i1 = idx; }
                    else if (val < l2) { l2 = val; i2 = idx; }
                }
                // index-carrying top-2 butterfly (no ballot needed)
                #pragma unroll
                for (int off = 32; off >= 1; off >>= 1) {
                    float ob1 = __shfl_xor(l1, off), ob2 = __shfl_xor(l2, off);
                    int   oc1 = __shfl_xor(i1, off), oc2 = __shfl_xor(i2, off);
                    bool tk = (ob1 < l1) || (ob1 == l1 && oc1 < i1);
                    float n1 = tk ? ob1 : l1; int ni1 = tk ? oc1 : i1;
                    float lz = tk ? l1  : ob1; int liz = tk ? i1  : oc1; // loser
                    float n2 = lz; int ni2 = liz;
                    if (l2  < n2) { n2 = l2;  ni2 = i2;  }
                    if (ob2 < n2) { n2 = ob2; ni2 = oc2; }
                    l1 = n1; i1 = ni1; l2 = n2; i2 = ni2;
                }
                float wmin = l1; int j0 = i1; int j0b = i2;
                if (wmin >= 1e37f) break;             // safety net
                int pj0 = pcol[PAD_IDX(j0)];
                if (pj0 < 0) { Df = wmin; jf = j0; break; }   // free column
                if ((j0 >> 4) == lane) used |= 1u << (j0 & 15);
                float uref = uu[PAD_IDX(j0)];
                float sft  = wmin - uref;
                // obtain row pj0 (reuse prefetch on hit)
                float cr[16];
                if (pf_j == j0) {
                    #pragma unroll
                    for (int k = 0; k < 16; ++k) cr[k] = pfr[k];
                    pf_j = -1;
                } else {
                    const float4* rr = reinterpret_cast<const float4*>(C + (size_t)pj0 * NSP + base);
                    #pragma unroll
                    for (int q = 0; q < 4; ++q) {
                        float4 c4 = rr[q];
                        cr[4*q+0] = c4.x; cr[4*q+1] = c4.y; cr[4*q+2] = c4.z; cr[4*q+3] = c4.w;
                    }
                }
                // speculative prefetch: runner-up column's owner row
                if (j0b < NSP && j0b != pf_j) {
                    int pj0b = pcol[PAD_IDX(j0b)];
                    if (pj0b >= 0) {
                        const float4* rb = reinterpret_cast<const float4*>(C + (size_t)pj0b * NSP + base);
                        #pragma unroll
                        for (int q = 0; q < 4; ++q) {
                            float4 c4 = rb[q];
                            pfr[4*q+0] = c4.x; pfr[4*q+1] = c4.y;
                            pfr[4*q+2] = c4.z; pfr[4*q+3] = c4.w;
                        }
                        pf_j = j0b;
                    } else pf_j = -1;
                }
                // relax
                #pragma unroll
                for (int k = 0; k < 16; ++k) {
                    float cand = sft + cr[k] - v[k];
                    bool upd = (cand < d[k]) && !((used >> k) & 1u);
                    if (upd) { d[k] = cand; way[PAD_IDX(base + k)] = j0; }
                }
            }

            // dual updates: v -= (Df - d), u[row] += (Df - d) on scanned cols
            if (jf >= 0) {
                #pragma unroll
                for (int k = 0; k < 16; ++k) {
                    if ((used >> k) & 1u) {
                        float diff = Df - d[k];
                        v[k] -= diff;
                        uu[PAD_IDX(base + k)] += diff;
                    }
                }
            }
        }
        __syncthreads();
        if (tid == 0 && jf >= 0) {            // tid 0 is lane 0 of wave 0
            int j = jf;
            for (int g = 0; g < NSP; ++g) {
                int jp = way[PAD_IDX(j)];
                if (jp < 0) { pcol[PAD_IDX(j)] = i; uu[PAD_IDX(j)] = ui + Df; break; }
                pcol[PAD_IDX(j)] = pcol[PAD_IDX(jp)];
                uu[PAD_IDX(j)]   = uu[PAD_IDX(jp)];
                j = jp;
            }
            done[i] = 1;
        }
        __syncthreads();
    }

    // ---- mean of matched costs (wave 0)
    if (tid < 64) {
        float acc = 0.f;
        #pragma unroll
        for (int k = 0; k < 16; ++k) {
            int j = base + k;
            if (j < NSRC) {
                int r = pcol[PAD_IDX(j)];
                if (r >= 0) acc += C[(size_t)r * NSP + j];
            }
        }
        #pragma unroll
        for (int off = 32; off >= 1; off >>= 1) acc += __shfl_xor(acc, off);
        if (lane == 0) out[b] = acc * (1.0f / NTGT);
    }
}

extern "C" void kernel_launch(void* const* d_in, const int* in_sizes, int n_in,
                              void* d_out, int out_size, void* d_ws, size_t ws_size,
                              hipStream_t stream) {
    const float* logits = (const float*)d_in[0];   // (32,1000,256) f32
    const int*   tcls   = (const int*)  d_in[1];   // (32,100) i32
    const float* sbox   = (const float*)d_in[2];   // (32,1000,4) f32
    const float* tbox   = (const float*)d_in[3];   // (32,100,4) f32
    float* out = (float*)d_out;                    // (32,) f32

    float* lse    = (float*)d_ws;                   // 32768 floats
    float* cost   = lse + 32768;                    // 32*100*1024 floats (~13.1 MB)
    float* urow_g = cost + (size_t)NB * NTGT * NSP; // 3200 floats
    int*   jmin_g = (int*)(urow_g + NB * NTGT);     // 3200 ints
    float* m2_g   = (float*)(jmin_g + NB * NTGT);   // 3200 floats

    lse_kernel <<<1000,      256, 0, stream>>>(logits, lse);
    cost_kernel<<<NB * NTGT, 256, 0, stream>>>(logits, tcls, sbox, tbox, lse, cost,
                                               urow_g, jmin_g, m2_g);
    lsa_kernel <<<NB,        512, 0, stream>>>(cost, urow_g, jmin_g, m2_g, out);
}